// Round 1
// baseline (178.146 us; speedup 1.0000x reference)
//
#include <hip/hip_runtime.h>

// STFT magnitude: out[f][t] = |sum_k xpad[t*200+k] * basis[f or f+401][k]|
// GEMM view: M = freqs (real+imag rows of basis), N = frames, K = 800.
// bf16 MFMA 16x16x32, fp32 accumulate, magnitude epilogue.

#define FL   800
#define HOP  200
#define CUT  401
#define NS   8000000
#define NT   40001          // number of frames
#define KSTEPS 25           // 800 / 32

#define FT   64             // freq tile (M)
#define TT   128            // frame tile (N)
#define SLICE ((TT - 1) * HOP + FL)   // 26200 samples per block
#define BROW 40             // padded basis row length in LDS (32 + 8)

typedef short short8 __attribute__((ext_vector_type(8)));
typedef short short4v __attribute__((ext_vector_type(4)));
typedef float float4v __attribute__((ext_vector_type(4)));

__device__ inline unsigned short f2bf(float f) {
    union { float f; unsigned u; } v; v.f = f;
    unsigned r = v.u + 0x7FFFu + ((v.u >> 16) & 1u);   // round-to-nearest-even
    return (unsigned short)(r >> 16);
}

__global__ __launch_bounds__(256, 2)
void stft_mag_kernel(const float* __restrict__ x,
                     const float* __restrict__ basis,
                     float* __restrict__ out) {
    __shared__ short sX[SLICE];            // frames slice, bf16
    __shared__ short sB[128 * BROW];       // basis k-slice: rows 0-63 real, 64-127 imag

    const int tid = threadIdx.x;
    const int tt  = blockIdx.x;            // frame tile index
    const int ft  = blockIdx.y;            // freq tile index
    const int t0  = tt * TT;
    const int f0  = ft * FT;

    // ---- stage frames slice once: fp32 -> bf16 with reflect padding ----
    const int base_g = t0 * HOP - (FL / 2);    // global sample index of sX[0]
    for (int i4 = tid; i4 < SLICE / 4; i4 += 256) {
        const int i = i4 * 4;
        const int g = base_g + i;
        short4v s;
        if (g >= 0 && g + 3 < NS) {
            const float4v v = *reinterpret_cast<const float4v*>(x + g);
            s[0] = f2bf(v[0]); s[1] = f2bf(v[1]);
            s[2] = f2bf(v[2]); s[3] = f2bf(v[3]);
        } else {
            #pragma unroll
            for (int j = 0; j < 4; ++j) {
                int gj = g + j;
                if (gj < 0) gj = -gj;                    // left reflect
                if (gj >= NS) gj = 2 * NS - 2 - gj;      // right reflect
                s[j] = f2bf(x[gj]);
            }
        }
        *reinterpret_cast<short4v*>(&sX[i]) = s;
    }

    const int wid  = tid >> 6;
    const int lane = tid & 63;
    const int wm   = wid >> 1;     // wave freq dim  (0..1) -> 32 freqs each
    const int wn   = wid & 1;      // wave frame dim (0..1) -> 64 frames each
    const int l15  = lane & 15;
    const int l4   = lane >> 4;

    float4v acc_r[2][4] = {};
    float4v acc_i[2][4] = {};

    // basis staging constants (per thread: one 16-float half-row)
    const int brow = tid >> 1;          // 0..127
    const int bhalf = tid & 1;          // 0 or 1
    const int bfr  = brow & 63;
    const int bfreq = f0 + bfr;
    const int bgrow = (brow < 64) ? bfreq : (CUT + bfreq);
    const bool bvalid = (bfreq < CUT);
    const float* bsrc0 = basis + (size_t)bgrow * FL + bhalf * 16;
    short* bdst = &sB[brow * BROW + bhalf * 16];

    for (int ks = 0; ks < KSTEPS; ++ks) {
        const int k0 = ks * 32;
        __syncthreads();   // previous iteration's fragment reads done

        // ---- stage basis k-slice: 128 rows x 32 cols, fp32 -> bf16 ----
        {
            short sbuf[16];
            if (bvalid) {
                const float* src = bsrc0 + k0;
                #pragma unroll
                for (int q = 0; q < 4; ++q) {
                    const float4v v = *reinterpret_cast<const float4v*>(src + q * 4);
                    sbuf[q*4+0] = f2bf(v[0]); sbuf[q*4+1] = f2bf(v[1]);
                    sbuf[q*4+2] = f2bf(v[2]); sbuf[q*4+3] = f2bf(v[3]);
                }
            } else {
                #pragma unroll
                for (int q = 0; q < 16; ++q) sbuf[q] = 0;
            }
            *reinterpret_cast<short8*>(bdst)     = *reinterpret_cast<short8*>(&sbuf[0]);
            *reinterpret_cast<short8*>(bdst + 8) = *reinterpret_cast<short8*>(&sbuf[8]);
        }
        __syncthreads();   // basis slice visible

        // ---- fragments ----
        short8 af_r[2], af_i[2], bfr_[4];
        #pragma unroll
        for (int mi = 0; mi < 2; ++mi) {
            const int row = wm * 32 + mi * 16 + l15;
            af_r[mi] = *reinterpret_cast<const short8*>(&sB[row * BROW + l4 * 8]);
            af_i[mi] = *reinterpret_cast<const short8*>(&sB[(row + 64) * BROW + l4 * 8]);
        }
        #pragma unroll
        for (int ni = 0; ni < 4; ++ni) {
            const int t = wn * 64 + ni * 16 + l15;
            bfr_[ni] = *reinterpret_cast<const short8*>(&sX[t * HOP + k0 + l4 * 8]);
        }

        // ---- MFMAs: 2 m-frags x 4 n-frags x {real, imag} ----
        #pragma unroll
        for (int mi = 0; mi < 2; ++mi) {
            #pragma unroll
            for (int ni = 0; ni < 4; ++ni) {
                acc_r[mi][ni] = __builtin_amdgcn_mfma_f32_16x16x32_bf16(
                    af_r[mi], bfr_[ni], acc_r[mi][ni], 0, 0, 0);
                acc_i[mi][ni] = __builtin_amdgcn_mfma_f32_16x16x32_bf16(
                    af_i[mi], bfr_[ni], acc_i[mi][ni], 0, 0, 0);
            }
        }
    }

    // ---- epilogue: magnitude + store (lanes 0-15 -> consecutive t, coalesced) ----
    #pragma unroll
    for (int mi = 0; mi < 2; ++mi) {
        #pragma unroll
        for (int r = 0; r < 4; ++r) {
            const int f = f0 + wm * 32 + mi * 16 + l4 * 4 + r;
            if (f >= CUT) continue;
            #pragma unroll
            for (int ni = 0; ni < 4; ++ni) {
                const int t = t0 + wn * 64 + ni * 16 + l15;
                if (t < NT) {
                    const float vr = acc_r[mi][ni][r];
                    const float vi = acc_i[mi][ni][r];
                    out[(size_t)f * NT + t] = sqrtf(vr * vr + vi * vi);
                }
            }
        }
    }
}

extern "C" void kernel_launch(void* const* d_in, const int* in_sizes, int n_in,
                              void* d_out, int out_size, void* d_ws, size_t ws_size,
                              hipStream_t stream) {
    const float* x     = (const float*)d_in[0];
    const float* basis = (const float*)d_in[1];
    float* out = (float*)d_out;

    const int ttiles = (NT + TT - 1) / TT;    // 313
    const int ftiles = (CUT + FT - 1) / FT;   // 7
    dim3 grid(ttiles, ftiles);
    stft_mag_kernel<<<grid, 256, 0, stream>>>(x, basis, out);
}

// Round 2
// 102.033 us; speedup vs baseline: 1.7460x; 1.7460x over previous
//
#include <hip/hip_runtime.h>

// STFT magnitude via bf16 MFMA GEMM.
// Round 2: pre-convert x -> padded bf16 xb (reflect done once) and basis ->
// padded bf16 bb in d_ws; hot kernel stages both with global_load_lds width=16
// (zero staging VALU), TT=96 / single sB buffer -> 48KB LDS -> 3 blocks/CU.

#define FL   800
#define HOP  200
#define CUT  401
#define NS   8000000
#define NT   40001
#define KSTEPS 25            // 800/32

#define FT   64              // freq tile (M)
#define TT   96              // frame tile (N)
#define SLICE_SH 20480       // sX shorts: 10 gload iters * 4096B (need 19800)
#define XBN  8016000         // xb length in shorts (NS + 800 + slack, mult of 8)
#define BBROWS 896           // bb rows: 0..447 real (401 used), 448..895 imag
#define BB_OFF 16032000      // byte offset of bb in ws (= XBN*2)

typedef short short8 __attribute__((ext_vector_type(8)));
typedef float float4v __attribute__((ext_vector_type(4)));

__device__ inline unsigned short f2bf(float f) {
    union { float f; unsigned u; } v; v.f = f;
    unsigned r = v.u + 0x7FFFu + ((v.u >> 16) & 1u);   // RNE
    return (unsigned short)(r >> 16);
}

// ---- prep 1: x (fp32) -> xb (bf16, reflect-padded by 400, zero-slack tail) ----
__global__ void prep_x(const float* __restrict__ x, short* __restrict__ xb) {
    const int n8 = XBN / 8;
    for (int j = blockIdx.x * blockDim.x + threadIdx.x; j < n8;
         j += gridDim.x * blockDim.x) {
        const int i = j * 8;            // xb index
        const int s = i - 400;          // sample index (xpad coords - 400)
        short8 o;
        if (s >= 0 && s + 7 < NS) {
            const float4v a = *reinterpret_cast<const float4v*>(x + s);
            const float4v b = *reinterpret_cast<const float4v*>(x + s + 4);
            o[0]=f2bf(a[0]); o[1]=f2bf(a[1]); o[2]=f2bf(a[2]); o[3]=f2bf(a[3]);
            o[4]=f2bf(b[0]); o[5]=f2bf(b[1]); o[6]=f2bf(b[2]); o[7]=f2bf(b[3]);
        } else {
            #pragma unroll
            for (int q = 0; q < 8; ++q) {
                int sq = s + q;
                if (sq < 0) sq = -sq;                       // left reflect
                else if (sq >= NS) sq = 2 * NS - 2 - sq;    // right reflect
                o[q] = f2bf(x[sq]);
            }
        }
        *reinterpret_cast<short8*>(xb + i) = o;
    }
}

// ---- prep 2: basis (802x800 fp32) -> bb (896x800 bf16, zero pad rows) ----
__global__ void prep_b(const float* __restrict__ basis, short* __restrict__ bb) {
    const int nch = BBROWS * 800 / 8;   // 89600
    for (int j = blockIdx.x * blockDim.x + threadIdx.x; j < nch;
         j += gridDim.x * blockDim.x) {
        const int row = j / 100;        // 100 chunks of 8 per row
        const int col = (j % 100) * 8;
        short8 o;
        int src = -1;
        if (row < CUT) src = row;                               // real
        else if (row >= 448 && row < 448 + CUT) src = row - 47; // imag -> 401..801
        if (src >= 0) {
            const float* p = basis + (size_t)src * 800 + col;
            const float4v a = *reinterpret_cast<const float4v*>(p);
            const float4v b = *reinterpret_cast<const float4v*>(p + 4);
            o[0]=f2bf(a[0]); o[1]=f2bf(a[1]); o[2]=f2bf(a[2]); o[3]=f2bf(a[3]);
            o[4]=f2bf(b[0]); o[5]=f2bf(b[1]); o[6]=f2bf(b[2]); o[7]=f2bf(b[3]);
        } else {
            #pragma unroll
            for (int q = 0; q < 8; ++q) o[q] = 0;
        }
        *reinterpret_cast<short8*>(bb + (size_t)row * 800 + col) = o;
    }
}

// ---- main GEMM kernel ----
__global__ __launch_bounds__(256, 3)
void stft_mag_kernel(const short* __restrict__ xb,
                     const short* __restrict__ bb,
                     float* __restrict__ out) {
    __shared__ short sX[SLICE_SH];       // frames slice (bf16), linear
    __shared__ short sB[128 * 32];       // basis k-slice: rows 0-63 real, 64-127 imag

    const int tid = threadIdx.x;
    const int t0  = blockIdx.x * TT;
    const int f0  = blockIdx.y * FT;

    // ---- stage sX once: 10 x global_load_lds width-16 ----
    {
        const short* src = xb + (size_t)t0 * HOP + tid * 8;
        short* dst = sX + tid * 8;
        #pragma unroll
        for (int it = 0; it < 10; ++it) {
            __builtin_amdgcn_global_load_lds(
                (const __attribute__((address_space(1))) unsigned int*)(src + it * 2048),
                (__attribute__((address_space(3))) unsigned int*)(dst + it * 2048),
                16, 0, 0);
        }
    }

    const int wid  = tid >> 6;
    const int lane = tid & 63;
    const int wm   = wid >> 1;       // 0..1 -> 32 freqs
    const int wn   = wid & 1;        // 0..1 -> 48 frames
    const int l15  = lane & 15;
    const int l4   = lane >> 4;

    // sB staging addresses (2 chunks per thread; per-lane global, linear LDS)
    const int c0 = tid, c1 = 256 + tid;
    const int row0 = c0 >> 2, row1 = c1 >> 2;
    const int g0 = (row0 < 64) ? (f0 + row0) : (448 + f0 + row0 - 64);
    const int g1 = (row1 < 64) ? (f0 + row1) : (448 + f0 + row1 - 64);
    const short* bsrc0 = bb + (size_t)g0 * 800 + (c0 & 3) * 8;
    const short* bsrc1 = bb + (size_t)g1 * 800 + (c1 & 3) * 8;
    short* bdst0 = sB + c0 * 8;
    short* bdst1 = sB + c1 * 8;

    // fragment LDS bases (shorts)
    const int ar0 = (wm * 32 + l15) * 32 + l4 * 8;          // mi=0 real
    const int ar1 = (wm * 32 + 16 + l15) * 32 + l4 * 8;     // mi=1 real
    const int xbase = (wn * 48 + l15) * HOP + l4 * 8;       // ni stride = 16*HOP

    float4v acc_r[2][3] = {};
    float4v acc_i[2][3] = {};

    for (int ks = 0; ks < KSTEPS; ++ks) {
        __syncthreads();   // prior fragment reads done -> safe to overwrite sB
        __builtin_amdgcn_global_load_lds(
            (const __attribute__((address_space(1))) unsigned int*)(bsrc0 + ks * 32),
            (__attribute__((address_space(3))) unsigned int*)bdst0, 16, 0, 0);
        __builtin_amdgcn_global_load_lds(
            (const __attribute__((address_space(1))) unsigned int*)(bsrc1 + ks * 32),
            (__attribute__((address_space(3))) unsigned int*)bdst1, 16, 0, 0);
        __syncthreads();   // drains vmcnt: sB (and sX on first iter) visible

        short8 a_r[2], a_i[2], xf[3];
        a_r[0] = *reinterpret_cast<const short8*>(&sB[ar0]);
        a_r[1] = *reinterpret_cast<const short8*>(&sB[ar1]);
        a_i[0] = *reinterpret_cast<const short8*>(&sB[ar0 + 64 * 32]);
        a_i[1] = *reinterpret_cast<const short8*>(&sB[ar1 + 64 * 32]);
        #pragma unroll
        for (int ni = 0; ni < 3; ++ni)
            xf[ni] = *reinterpret_cast<const short8*>(&sX[xbase + ni * 16 * HOP + ks * 32]);

        #pragma unroll
        for (int mi = 0; mi < 2; ++mi) {
            #pragma unroll
            for (int ni = 0; ni < 3; ++ni) {
                acc_r[mi][ni] = __builtin_amdgcn_mfma_f32_16x16x32_bf16(
                    a_r[mi], xf[ni], acc_r[mi][ni], 0, 0, 0);
                acc_i[mi][ni] = __builtin_amdgcn_mfma_f32_16x16x32_bf16(
                    a_i[mi], xf[ni], acc_i[mi][ni], 0, 0, 0);
            }
        }
    }

    // ---- epilogue: magnitude + coalesced dword stores ----
    #pragma unroll
    for (int mi = 0; mi < 2; ++mi) {
        #pragma unroll
        for (int r = 0; r < 4; ++r) {
            const int f = f0 + wm * 32 + mi * 16 + l4 * 4 + r;
            if (f >= CUT) continue;
            #pragma unroll
            for (int ni = 0; ni < 3; ++ni) {
                const int t = t0 + wn * 48 + ni * 16 + l15;
                if (t < NT) {
                    const float vr = acc_r[mi][ni][r];
                    const float vi = acc_i[mi][ni][r];
                    out[(size_t)f * NT + t] = sqrtf(vr * vr + vi * vi);
                }
            }
        }
    }
}

extern "C" void kernel_launch(void* const* d_in, const int* in_sizes, int n_in,
                              void* d_out, int out_size, void* d_ws, size_t ws_size,
                              hipStream_t stream) {
    const float* x     = (const float*)d_in[0];
    const float* basis = (const float*)d_in[1];
    float* out = (float*)d_out;

    short* xb = (short*)d_ws;
    short* bb = (short*)((char*)d_ws + BB_OFF);

    prep_x<<<2048, 256, 0, stream>>>(x, xb);
    prep_b<<<350, 256, 0, stream>>>(basis, bb);

    const int ttiles = (NT + TT - 1) / TT;    // 417
    const int ftiles = (CUT + FT - 1) / FT;   // 7
    dim3 grid(ttiles, ftiles);
    stft_mag_kernel<<<grid, 256, 0, stream>>>(xb, bb, out);
}

// Round 3
// 96.136 us; speedup vs baseline: 1.8531x; 1.0613x over previous
//
#include <hip/hip_runtime.h>

// STFT magnitude via bf16 MFMA GEMM.
// Round 3: counted-vmcnt triple-buffered basis pipeline (one raw s_barrier +
// vmcnt(2) per k-step, never vmcnt(0) in-loop), bank-conflict-free sB via
// both-sides involution swizzle (linear gload_lds dest + pre-swizzled global
// source + swizzled read), TT=128 with 32x64 per-wave tiles (8 reads : 16 MFMA).

#define FL   800
#define HOP  200
#define CUT  401
#define NS   8000000
#define NT   40001
#define KSTEPS 25            // 800/32

#define FT   64              // freq tile (M)
#define TT   128             // frame tile (N)
#define SLICE_SH 26624       // sX shorts: 13 gload iters * 4096B (need 26200)
#define XBN  8016000         // xb length in shorts
#define BB_OFF 16032000      // byte offset of bb in ws (= XBN*2)

typedef short short8 __attribute__((ext_vector_type(8)));
typedef float float4v __attribute__((ext_vector_type(4)));

#define GU32 const __attribute__((address_space(1))) unsigned int*
#define LU32 __attribute__((address_space(3))) unsigned int*

__device__ inline unsigned short f2bf(float f) {
    union { float f; unsigned u; } v; v.f = f;
    unsigned r = v.u + 0x7FFFu + ((v.u >> 16) & 1u);   // RNE
    return (unsigned short)(r >> 16);
}

// ---- prep 1: x (fp32) -> xb (bf16, reflect-padded by 400) ----
__global__ void prep_x(const float* __restrict__ x, short* __restrict__ xb) {
    const int n8 = XBN / 8;
    for (int j = blockIdx.x * blockDim.x + threadIdx.x; j < n8;
         j += gridDim.x * blockDim.x) {
        const int i = j * 8;
        const int s = i - 400;
        short8 o;
        if (s >= 0 && s + 7 < NS) {
            const float4v a = *reinterpret_cast<const float4v*>(x + s);
            const float4v b = *reinterpret_cast<const float4v*>(x + s + 4);
            o[0]=f2bf(a[0]); o[1]=f2bf(a[1]); o[2]=f2bf(a[2]); o[3]=f2bf(a[3]);
            o[4]=f2bf(b[0]); o[5]=f2bf(b[1]); o[6]=f2bf(b[2]); o[7]=f2bf(b[3]);
        } else {
            #pragma unroll
            for (int q = 0; q < 8; ++q) {
                int sq = s + q;
                if (sq < 0) sq = -sq;
                else if (sq >= NS) sq = 2 * NS - 2 - sq;
                o[q] = f2bf(x[sq]);
            }
        }
        *reinterpret_cast<short8*>(xb + i) = o;
    }
}

// ---- prep 2: basis (802x800 fp32) -> bb (896x800 bf16, zero pad rows) ----
__global__ void prep_b(const float* __restrict__ basis, short* __restrict__ bb) {
    const int nch = 896 * 100;          // 8-short chunks
    for (int j = blockIdx.x * blockDim.x + threadIdx.x; j < nch;
         j += gridDim.x * blockDim.x) {
        const int row = j / 100;
        const int col = (j % 100) * 8;
        short8 o;
        int src = -1;
        if (row < CUT) src = row;
        else if (row >= 448 && row < 448 + CUT) src = row - 47;
        if (src >= 0) {
            const float* p = basis + (size_t)src * 800 + col;
            const float4v a = *reinterpret_cast<const float4v*>(p);
            const float4v b = *reinterpret_cast<const float4v*>(p + 4);
            o[0]=f2bf(a[0]); o[1]=f2bf(a[1]); o[2]=f2bf(a[2]); o[3]=f2bf(a[3]);
            o[4]=f2bf(b[0]); o[5]=f2bf(b[1]); o[6]=f2bf(b[2]); o[7]=f2bf(b[3]);
        } else {
            #pragma unroll
            for (int q = 0; q < 8; ++q) o[q] = 0;
        }
        *reinterpret_cast<short8*>(bb + (size_t)row * 800 + col) = o;
    }
}

#define MF(A, X, C) C = __builtin_amdgcn_mfma_f32_16x16x32_bf16((A), (X), (C), 0, 0, 0)

// pipeline body: wait pair KS, barrier, read frags, optionally issue pair IKS
// into IBP, then 16 MFMAs.
#define BODY(KS, BP, IKS, IBP, DOISS)                                           \
  {                                                                             \
    asm volatile("s_waitcnt vmcnt(2)" ::: "memory");                            \
    __builtin_amdgcn_s_barrier();                                               \
    asm volatile("" ::: "memory");                                              \
    const short* bp_ = (BP);                                                    \
    const short8 ar0 = *reinterpret_cast<const short8*>(bp_ + oar0);            \
    const short8 ar1 = *reinterpret_cast<const short8*>(bp_ + oar1);            \
    const short8 ai0 = *reinterpret_cast<const short8*>(bp_ + oai0);            \
    const short8 ai1 = *reinterpret_cast<const short8*>(bp_ + oai1);            \
    const short8 xf0 = *reinterpret_cast<const short8*>(&sX[xbase + 0*3200 + (KS)*32]); \
    const short8 xf1 = *reinterpret_cast<const short8*>(&sX[xbase + 1*3200 + (KS)*32]); \
    const short8 xf2 = *reinterpret_cast<const short8*>(&sX[xbase + 2*3200 + (KS)*32]); \
    const short8 xf3 = *reinterpret_cast<const short8*>(&sX[xbase + 3*3200 + (KS)*32]); \
    if (DOISS) {                                                                \
      __builtin_amdgcn_global_load_lds((GU32)(bsrc0 + (IKS)*32),                \
          (LU32)((IBP) + tid*8), 16, 0, 0);                                     \
      __builtin_amdgcn_global_load_lds((GU32)(bsrc1 + (IKS)*32),                \
          (LU32)((IBP) + 2048 + tid*8), 16, 0, 0);                              \
    }                                                                           \
    MF(ar0, xf0, acc_r[0][0]); MF(ar0, xf1, acc_r[0][1]);                       \
    MF(ar0, xf2, acc_r[0][2]); MF(ar0, xf3, acc_r[0][3]);                       \
    MF(ar1, xf0, acc_r[1][0]); MF(ar1, xf1, acc_r[1][1]);                       \
    MF(ar1, xf2, acc_r[1][2]); MF(ar1, xf3, acc_r[1][3]);                       \
    MF(ai0, xf0, acc_i[0][0]); MF(ai0, xf1, acc_i[0][1]);                       \
    MF(ai0, xf2, acc_i[0][2]); MF(ai0, xf3, acc_i[0][3]);                       \
    MF(ai1, xf0, acc_i[1][0]); MF(ai1, xf1, acc_i[1][1]);                       \
    MF(ai1, xf2, acc_i[1][2]); MF(ai1, xf3, acc_i[1][3]);                       \
  }

__global__ __launch_bounds__(256, 2)
void stft_mag_kernel(const short* __restrict__ xb,
                     const short* __restrict__ bb,
                     float* __restrict__ out) {
    __shared__ short sX[SLICE_SH];
    __shared__ short sB0[128 * 32];
    __shared__ short sB1[128 * 32];
    __shared__ short sB2[128 * 32];

    const int tid = threadIdx.x;
    const int t0  = blockIdx.x * TT;
    const int f0  = blockIdx.y * FT;

    // ---- sB staging source (pre-swizzled slot so linear LDS dest + swizzled
    //      read form the same involution: slot' = slot ^ ((row>>1)&3)) ----
    const int rowc  = tid >> 2;                       // 0..63 (chunk row)
    const int slot0 = (tid & 3) ^ ((tid >> 3) & 3);
    const short* bsrc0 = bb + (size_t)(f0 + rowc) * 800 + slot0 * 8;        // real
    const short* bsrc1 = bb + (size_t)(448 + f0 + rowc) * 800 + slot0 * 8;  // imag

    // ---- prologue: pair0 -> sB0, sX (13 loads), pair1 -> sB1 ----
    __builtin_amdgcn_global_load_lds((GU32)(bsrc0), (LU32)(sB0 + tid*8), 16, 0, 0);
    __builtin_amdgcn_global_load_lds((GU32)(bsrc1), (LU32)(sB0 + 2048 + tid*8), 16, 0, 0);
    {
        const short* src = xb + (size_t)t0 * HOP + tid * 8;
        short* dst = sX + tid * 8;
        #pragma unroll
        for (int it = 0; it < 13; ++it) {
            __builtin_amdgcn_global_load_lds((GU32)(src + it * 2048),
                                             (LU32)(dst + it * 2048), 16, 0, 0);
        }
    }
    __builtin_amdgcn_global_load_lds((GU32)(bsrc0 + 32), (LU32)(sB1 + tid*8), 16, 0, 0);
    __builtin_amdgcn_global_load_lds((GU32)(bsrc1 + 32), (LU32)(sB1 + 2048 + tid*8), 16, 0, 0);

    const int wid  = tid >> 6;
    const int lane = tid & 63;
    const int wm   = wid >> 1;       // 0..1 -> 32 freqs
    const int wn   = wid & 1;        // 0..1 -> 64 frames
    const int l15  = lane & 15;
    const int l4   = lane >> 4;

    // fragment LDS offsets (shorts); swizzled chunk = row*4 + (l4 ^ ((row>>1)&3))
    const int rr0 = wm * 32 + l15;
    const int rr1 = wm * 32 + 16 + l15;
    const int oar0 = (rr0 * 4 + (l4 ^ ((rr0 >> 1) & 3))) * 8;
    const int oar1 = (rr1 * 4 + (l4 ^ ((rr1 >> 1) & 3))) * 8;
    const int oai0 = ((64 + rr0) * 4 + (l4 ^ (((64 + rr0) >> 1) & 3))) * 8;
    const int oai1 = ((64 + rr1) * 4 + (l4 ^ (((64 + rr1) >> 1) & 3))) * 8;
    const int xbase = (wn * 64 + l15) * HOP + l4 * 8;   // + ni*16*HOP + ks*32

    float4v acc_r[2][4] = {};
    float4v acc_i[2][4] = {};

    // ---- main pipeline: 25 k-steps, unroll by 3 for compile-time buffers ----
    for (int jj = 0; jj < 24; jj += 3) {
        BODY(jj,     sB0, jj + 2,                      sB2, 1);
        BODY(jj + 1, sB1, (jj + 3 <= 24 ? jj + 3 : 24), sB0, 1);
        BODY(jj + 2, sB2, (jj + 4 <= 24 ? jj + 4 : 24), sB1, 1);
    }
    BODY(24, sB0, 0, sB1, 0);

    // ---- epilogue: magnitude + coalesced stores ----
    #pragma unroll
    for (int mi = 0; mi < 2; ++mi) {
        #pragma unroll
        for (int r = 0; r < 4; ++r) {
            const int f = f0 + wm * 32 + mi * 16 + l4 * 4 + r;
            if (f >= CUT) continue;
            #pragma unroll
            for (int ni = 0; ni < 4; ++ni) {
                const int t = t0 + wn * 64 + ni * 16 + l15;
                if (t < NT) {
                    const float vr = (mi == 0 ? acc_r[0][ni][r] : acc_r[1][ni][r]);
                    const float vi = (mi == 0 ? acc_i[0][ni][r] : acc_i[1][ni][r]);
                    out[(size_t)f * NT + t] = sqrtf(vr * vr + vi * vi);
                }
            }
        }
    }
}

extern "C" void kernel_launch(void* const* d_in, const int* in_sizes, int n_in,
                              void* d_out, int out_size, void* d_ws, size_t ws_size,
                              hipStream_t stream) {
    const float* x     = (const float*)d_in[0];
    const float* basis = (const float*)d_in[1];
    float* out = (float*)d_out;

    short* xb = (short*)d_ws;
    short* bb = (short*)((char*)d_ws + BB_OFF);

    prep_x<<<2048, 256, 0, stream>>>(x, xb);
    prep_b<<<350, 256, 0, stream>>>(basis, bb);

    const int ttiles = (NT + TT - 1) / TT;    // 313
    const int ftiles = (CUT + FT - 1) / FT;   // 7
    dim3 grid(ttiles, ftiles);
    stft_mag_kernel<<<grid, 256, 0, stream>>>(xb, bb, out);
}

// Round 4
// 83.719 us; speedup vs baseline: 2.1279x; 1.1483x over previous
//
#include <hip/hip_runtime.h>

// STFT magnitude via bf16 MFMA GEMM.
// Round 4: register double-buffered fragments — during step j's 16 MFMAs,
// issue the 8 ds_reads for step j+1 (sX is barrier-free; sB pair(j+1) is
// proven landed via issue-at-top + vmcnt(2)). lgkmcnt(0) folded into the
// pre-barrier wait => no ds_read crosses a barrier => rotation race-free.
// T5 setprio around the pure-reg MFMA cluster. Bijective XCD-chunked grid
// swizzle (y-fastest) for xb L2 reuse.

#define FL   800
#define HOP  200
#define CUT  401
#define NS   8000000
#define NT   40001
#define KSTEPS 25            // 800/32

#define FT   64              // freq tile (M)
#define TT   128             // frame tile (N)
#define SLICE_SH 26624       // sX shorts: 13 gload iters * 4096B (need 26200)
#define XBN  8016000         // xb length in shorts
#define BB_OFF 16032000      // byte offset of bb in ws (= XBN*2)

typedef short short8 __attribute__((ext_vector_type(8)));
typedef float float4v __attribute__((ext_vector_type(4)));

#define GU32 const __attribute__((address_space(1))) unsigned int*
#define LU32 __attribute__((address_space(3))) unsigned int*

__device__ inline unsigned short f2bf(float f) {
    union { float f; unsigned u; } v; v.f = f;
    unsigned r = v.u + 0x7FFFu + ((v.u >> 16) & 1u);   // RNE
    return (unsigned short)(r >> 16);
}

// ---- prep 1: x (fp32) -> xb (bf16, reflect-padded by 400) ----
__global__ void prep_x(const float* __restrict__ x, short* __restrict__ xb) {
    const int n8 = XBN / 8;
    for (int j = blockIdx.x * blockDim.x + threadIdx.x; j < n8;
         j += gridDim.x * blockDim.x) {
        const int i = j * 8;
        const int s = i - 400;
        short8 o;
        if (s >= 0 && s + 7 < NS) {
            const float4v a = *reinterpret_cast<const float4v*>(x + s);
            const float4v b = *reinterpret_cast<const float4v*>(x + s + 4);
            o[0]=f2bf(a[0]); o[1]=f2bf(a[1]); o[2]=f2bf(a[2]); o[3]=f2bf(a[3]);
            o[4]=f2bf(b[0]); o[5]=f2bf(b[1]); o[6]=f2bf(b[2]); o[7]=f2bf(b[3]);
        } else {
            #pragma unroll
            for (int q = 0; q < 8; ++q) {
                int sq = s + q;
                if (sq < 0) sq = -sq;
                else if (sq >= NS) sq = 2 * NS - 2 - sq;
                o[q] = f2bf(x[sq]);
            }
        }
        *reinterpret_cast<short8*>(xb + i) = o;
    }
}

// ---- prep 2: basis (802x800 fp32) -> bb (896x800 bf16, zero pad rows) ----
__global__ void prep_b(const float* __restrict__ basis, short* __restrict__ bb) {
    const int nch = 896 * 100;
    for (int j = blockIdx.x * blockDim.x + threadIdx.x; j < nch;
         j += gridDim.x * blockDim.x) {
        const int row = j / 100;
        const int col = (j % 100) * 8;
        short8 o;
        int src = -1;
        if (row < CUT) src = row;
        else if (row >= 448 && row < 448 + CUT) src = row - 47;
        if (src >= 0) {
            const float* p = basis + (size_t)src * 800 + col;
            const float4v a = *reinterpret_cast<const float4v*>(p);
            const float4v b = *reinterpret_cast<const float4v*>(p + 4);
            o[0]=f2bf(a[0]); o[1]=f2bf(a[1]); o[2]=f2bf(a[2]); o[3]=f2bf(a[3]);
            o[4]=f2bf(b[0]); o[5]=f2bf(b[1]); o[6]=f2bf(b[2]); o[7]=f2bf(b[3]);
        } else {
            #pragma unroll
            for (int q = 0; q < 8; ++q) o[q] = 0;
        }
        *reinterpret_cast<short8*>(bb + (size_t)row * 800 + col) = o;
    }
}

#define MF(A, X, C) C = __builtin_amdgcn_mfma_f32_16x16x32_bf16((A), (X), (C), 0, 0, 0)

// One pipeline step. FC = fragments for step KS (in regs). FN = fragments for
// step KS+1 (prefetched here from NXTBUF/sX). ISSBUF receives pair KS+2.
#define BODY(KS, FC, FN, NXTBUF, ISSBUF)                                        \
  {                                                                             \
    if ((KS) <= 22) {                                                           \
      __builtin_amdgcn_global_load_lds((GU32)(bsrc0 + ((KS)+2)*32),             \
          (LU32)((ISSBUF) + tid*8), 16, 0, 0);                                  \
      __builtin_amdgcn_global_load_lds((GU32)(bsrc1 + ((KS)+2)*32),             \
          (LU32)((ISSBUF) + 2048 + tid*8), 16, 0, 0);                           \
      asm volatile("s_waitcnt vmcnt(2) lgkmcnt(0)" ::: "memory");               \
    } else {                                                                    \
      asm volatile("s_waitcnt vmcnt(0) lgkmcnt(0)" ::: "memory");               \
    }                                                                           \
    __builtin_amdgcn_s_barrier();                                               \
    asm volatile("" ::: "memory");                                              \
    {                                                                           \
      const short* np_ = (NXTBUF);                                              \
      FN[0] = *reinterpret_cast<const short8*>(np_ + oar0);                     \
      FN[1] = *reinterpret_cast<const short8*>(np_ + oar1);                     \
      FN[2] = *reinterpret_cast<const short8*>(np_ + oai0);                     \
      FN[3] = *reinterpret_cast<const short8*>(np_ + oai1);                     \
      FN[4] = *reinterpret_cast<const short8*>(&sX[xbase + 0*3200 + ((KS)+1)*32]); \
      FN[5] = *reinterpret_cast<const short8*>(&sX[xbase + 1*3200 + ((KS)+1)*32]); \
      FN[6] = *reinterpret_cast<const short8*>(&sX[xbase + 2*3200 + ((KS)+1)*32]); \
      FN[7] = *reinterpret_cast<const short8*>(&sX[xbase + 3*3200 + ((KS)+1)*32]); \
    }                                                                           \
    __builtin_amdgcn_s_setprio(1);                                              \
    MF(FC[0], FC[4], acc_r[0][0]); MF(FC[0], FC[5], acc_r[0][1]);               \
    MF(FC[0], FC[6], acc_r[0][2]); MF(FC[0], FC[7], acc_r[0][3]);               \
    MF(FC[1], FC[4], acc_r[1][0]); MF(FC[1], FC[5], acc_r[1][1]);               \
    MF(FC[1], FC[6], acc_r[1][2]); MF(FC[1], FC[7], acc_r[1][3]);               \
    MF(FC[2], FC[4], acc_i[0][0]); MF(FC[2], FC[5], acc_i[0][1]);               \
    MF(FC[2], FC[6], acc_i[0][2]); MF(FC[2], FC[7], acc_i[0][3]);               \
    MF(FC[3], FC[4], acc_i[1][0]); MF(FC[3], FC[5], acc_i[1][1]);               \
    MF(FC[3], FC[6], acc_i[1][2]); MF(FC[3], FC[7], acc_i[1][3]);               \
    __builtin_amdgcn_s_setprio(0);                                              \
  }

__global__ __launch_bounds__(256, 2)
void stft_mag_kernel(const short* __restrict__ xb,
                     const short* __restrict__ bb,
                     float* __restrict__ out) {
    __shared__ short sX[SLICE_SH];
    __shared__ short sB0[128 * 32];
    __shared__ short sB1[128 * 32];
    __shared__ short sB2[128 * 32];

    const int tid = threadIdx.x;

    // ---- bijective XCD-chunked swizzle (nwg=2191, 8 XCDs), y-fastest ----
    const int nwg = 313 * 7;
    const int q = nwg >> 3, r = nwg & 7;          // 273, 7
    const int bid = blockIdx.x;
    const int xcd = bid & 7, idx = bid >> 3;
    const int wgid = (xcd < r ? xcd * (q + 1) : r * (q + 1) + (xcd - r) * q) + idx;
    const int t0 = (wgid / 7) * TT;
    const int f0 = (wgid % 7) * FT;

    // ---- sB staging source (pre-swizzled slot; involution slot'=slot^((row>>1)&3)) ----
    const int rowc  = tid >> 2;
    const int slot0 = (tid & 3) ^ ((tid >> 3) & 3);
    const short* bsrc0 = bb + (size_t)(f0 + rowc) * 800 + slot0 * 8;        // real
    const short* bsrc1 = bb + (size_t)(448 + f0 + rowc) * 800 + slot0 * 8;  // imag

    // ---- prologue: pair0 -> sB0, sX (13 loads), pair1 -> sB1 ----
    __builtin_amdgcn_global_load_lds((GU32)(bsrc0), (LU32)(sB0 + tid*8), 16, 0, 0);
    __builtin_amdgcn_global_load_lds((GU32)(bsrc1), (LU32)(sB0 + 2048 + tid*8), 16, 0, 0);
    {
        const short* src = xb + (size_t)t0 * HOP + tid * 8;
        short* dst = sX + tid * 8;
        #pragma unroll
        for (int it = 0; it < 13; ++it) {
            __builtin_amdgcn_global_load_lds((GU32)(src + it * 2048),
                                             (LU32)(dst + it * 2048), 16, 0, 0);
        }
    }
    __builtin_amdgcn_global_load_lds((GU32)(bsrc0 + 32), (LU32)(sB1 + tid*8), 16, 0, 0);
    __builtin_amdgcn_global_load_lds((GU32)(bsrc1 + 32), (LU32)(sB1 + 2048 + tid*8), 16, 0, 0);

    const int wid  = tid >> 6;
    const int lane = tid & 63;
    const int wm   = wid >> 1;
    const int wn   = wid & 1;
    const int l15  = lane & 15;
    const int l4   = lane >> 4;

    // fragment LDS offsets (shorts); swizzled chunk = row*4 + (l4 ^ ((row>>1)&3))
    const int rr0 = wm * 32 + l15;
    const int rr1 = wm * 32 + 16 + l15;
    const int oar0 = (rr0 * 4 + (l4 ^ ((rr0 >> 1) & 3))) * 8;
    const int oar1 = (rr1 * 4 + (l4 ^ ((rr1 >> 1) & 3))) * 8;
    const int oai0 = ((64 + rr0) * 4 + (l4 ^ (((64 + rr0) >> 1) & 3))) * 8;
    const int oai1 = ((64 + rr1) * 4 + (l4 ^ (((64 + rr1) >> 1) & 3))) * 8;
    const int xbase = (wn * 64 + l15) * HOP + l4 * 8;

    float4v acc_r[2][4] = {};
    float4v acc_i[2][4] = {};

    short8 FA[8], FB[8];

    // ---- pre-loop: wait pair0+sX, read fr(0) into FA ----
    asm volatile("s_waitcnt vmcnt(2)" ::: "memory");
    __builtin_amdgcn_s_barrier();
    asm volatile("" ::: "memory");
    FA[0] = *reinterpret_cast<const short8*>(sB0 + oar0);
    FA[1] = *reinterpret_cast<const short8*>(sB0 + oar1);
    FA[2] = *reinterpret_cast<const short8*>(sB0 + oai0);
    FA[3] = *reinterpret_cast<const short8*>(sB0 + oai1);
    FA[4] = *reinterpret_cast<const short8*>(&sX[xbase + 0*3200]);
    FA[5] = *reinterpret_cast<const short8*>(&sX[xbase + 1*3200]);
    FA[6] = *reinterpret_cast<const short8*>(&sX[xbase + 2*3200]);
    FA[7] = *reinterpret_cast<const short8*>(&sX[xbase + 3*3200]);

    // ---- main pipeline: steps 0..23 (buffers cycle 0,1,2; frags A/B) ----
    #pragma unroll
    for (int jj = 0; jj < 24; jj += 6) {
        BODY(jj + 0, FA, FB, sB1, sB2);
        BODY(jj + 1, FB, FA, sB2, sB0);
        BODY(jj + 2, FA, FB, sB0, sB1);
        BODY(jj + 3, FB, FA, sB1, sB2);
        BODY(jj + 4, FA, FB, sB2, sB0);
        BODY(jj + 5, FB, FA, sB0, sB1);
    }

    // ---- tail: step 24 on FA (prefetched at step 23), no barrier needed ----
    __builtin_amdgcn_s_setprio(1);
    MF(FA[0], FA[4], acc_r[0][0]); MF(FA[0], FA[5], acc_r[0][1]);
    MF(FA[0], FA[6], acc_r[0][2]); MF(FA[0], FA[7], acc_r[0][3]);
    MF(FA[1], FA[4], acc_r[1][0]); MF(FA[1], FA[5], acc_r[1][1]);
    MF(FA[1], FA[6], acc_r[1][2]); MF(FA[1], FA[7], acc_r[1][3]);
    MF(FA[2], FA[4], acc_i[0][0]); MF(FA[2], FA[5], acc_i[0][1]);
    MF(FA[2], FA[6], acc_i[0][2]); MF(FA[2], FA[7], acc_i[0][3]);
    MF(FA[3], FA[4], acc_i[1][0]); MF(FA[3], FA[5], acc_i[1][1]);
    MF(FA[3], FA[6], acc_i[1][2]); MF(FA[3], FA[7], acc_i[1][3]);
    __builtin_amdgcn_s_setprio(0);

    // ---- epilogue: magnitude + coalesced stores ----
    #pragma unroll
    for (int mi = 0; mi < 2; ++mi) {
        #pragma unroll
        for (int rr = 0; rr < 4; ++rr) {
            const int f = f0 + wm * 32 + mi * 16 + l4 * 4 + rr;
            if (f >= CUT) continue;
            #pragma unroll
            for (int ni = 0; ni < 4; ++ni) {
                const int t = t0 + wn * 64 + ni * 16 + l15;
                if (t < NT) {
                    const float vr = (mi == 0 ? acc_r[0][ni][rr] : acc_r[1][ni][rr]);
                    const float vi = (mi == 0 ? acc_i[0][ni][rr] : acc_i[1][ni][rr]);
                    out[(size_t)f * NT + t] = sqrtf(vr * vr + vi * vi);
                }
            }
        }
    }
}

extern "C" void kernel_launch(void* const* d_in, const int* in_sizes, int n_in,
                              void* d_out, int out_size, void* d_ws, size_t ws_size,
                              hipStream_t stream) {
    const float* x     = (const float*)d_in[0];
    const float* basis = (const float*)d_in[1];
    float* out = (float*)d_out;

    short* xb = (short*)d_ws;
    short* bb = (short*)((char*)d_ws + BB_OFF);

    prep_x<<<2048, 256, 0, stream>>>(x, xb);
    prep_b<<<350, 256, 0, stream>>>(basis, bb);

    stft_mag_kernel<<<313 * 7, 256, 0, stream>>>(xb, bb, out);
}